// Round 8
// baseline (303.205 us; speedup 1.0000x reference)
//
#include <hip/hip_runtime.h>
#include <cstddef>
#include <cstdint>

typedef __attribute__((ext_vector_type(8))) short bf16x8;   // 8 bf16 = 4 VGPR
typedef __attribute__((ext_vector_type(16))) float f32x16;  // MFMA 32x32 acc

static constexpr float LN2 = 0.69314718055994530942f;
static constexpr float INV_LN2 = 1.44269504088896340736f;

__device__ __forceinline__ unsigned short f2bf(float f) {
  unsigned int u = __float_as_uint(f);
  u += 0x7fffu + ((u >> 16) & 1u);   // RNE
  return (unsigned short)(u >> 16);
}

// v_cvt_pk_bf16_f32 (gfx950): D[15:0]=bf16(a), D[31:16]=bf16(b), RNE
__device__ __forceinline__ unsigned int cvt_pk_bf16(float a, float b) {
  unsigned int r;
  asm("v_cvt_pk_bf16_f32 %0, %1, %2" : "=v"(r) : "v"(a), "v"(b));
  return r;
}

__device__ __forceinline__ float hw_exp2(float x) {
  float r;
  asm("v_exp_f32 %0, %1" : "=v"(r) : "v"(x));
  return r;
}
__device__ __forceinline__ float hw_log2(float x) {
  float r;
  asm("v_log_f32 %0, %1" : "=v"(r) : "v"(x));
  return r;
}

// softplus(x)-ln2 = max(x,0)-ln2 + ln2*log2(1+2^(-|x|/ln2)); rel err ~1e-5
__device__ __forceinline__ float shsp(float x) {
  float t = hw_exp2(-fabsf(x) * INV_LN2);
  float l = hw_log2(1.0f + t);
  return fmaf(LN2, l, fmaxf(x, 0.0f) - LN2);
}

// async 16B global -> LDS (lane l writes lds + l*16)
__device__ __forceinline__ void async_copy16(const void* g, void* l) {
  __builtin_amdgcn_global_load_lds(
      (const __attribute__((address_space(1))) void*)g,
      (__attribute__((address_space(3))) void*)l, 16, 0, 0);
}

// ---- prep: h (N*64 f32) -> bf16 ----
__global__ void prep_h_kernel(const float* __restrict__ h,
                              unsigned short* __restrict__ hbf, int n4) {
  int i = blockIdx.x * 256 + threadIdx.x;
  if (i < n4) {
    float4 v = reinterpret_cast<const float4*>(h)[i];
    uint2 o;
    o.x = cvt_pk_bf16(v.x, v.y);
    o.y = cvt_pk_bf16(v.z, v.w);
    reinterpret_cast<uint2*>(hbf)[i] = o;
  }
}

// ---- prep: pack W1^T, W2^T into MFMA-fragment order (bf16), kk-major ----
__global__ void prep_w_kernel(const float* __restrict__ W1,
                              const float* __restrict__ W2,
                              unsigned short* __restrict__ Wp1,
                              unsigned short* __restrict__ Wp2) {
  int j = blockIdx.x * 256 + threadIdx.x;
  if (j < 48 * 64) {
    int f  = j / 64;
    int l  = j % 64;
    int kk = f >> 2;
    int mt = f & 3;
    int col = mt * 32 + (l & 31);
    int kb  = kk * 16 + (l >> 5) * 8;
    #pragma unroll
    for (int i = 0; i < 8; ++i)
      Wp1[(size_t)j * 8 + i] = f2bf(W1[(size_t)(kb + i) * 128 + col]);
  } else if (j < 48 * 64 + 16 * 64) {
    int jj = j - 48 * 64;
    int f  = jj / 64;
    int l  = jj % 64;
    int kk = f >> 1;
    int mt = f & 1;
    int oc = mt * 32 + (l & 31);
    int kb = kk * 16 + (l >> 5) * 8;
    #pragma unroll
    for (int i = 0; i < 8; ++i)
      Wp2[(size_t)jj * 8 + i] = f2bf(W2[(size_t)(kb + i) * 64 + oc]);
  }
}

// ---- main fused kernel: R7 structure + register-resident prefetch ----
// 512 threads, 1 block/CU. LDS 144KB: [0,48K) W1 frags (staged once);
// per-wave 12KB (HAw 8K h->X->out lifecycle, EAw 4K). Waves free-run over
// CONTIGUOUS tile runs; next tile's idx/ea/h prefetched into VGPR banks
// (A/B, statically indexed) while current tile computes. 8-wave LDS cap
// makes the extra ~100 VGPRs occupancy-free.
__global__ __launch_bounds__(512, 2)
void edge_mlp_kernel(const float* __restrict__ ea,
                     const int* __restrict__ eidx,
                     const float* __restrict__ b1,
                     const float* __restrict__ b2,
                     const unsigned short* __restrict__ hbf,
                     const unsigned short* __restrict__ Wp1,
                     const unsigned short* __restrict__ Wp2,
                     float* __restrict__ out,
                     int E, int ntiles) {
  __shared__ __align__(16) unsigned char LDS[147456];

  const int tid  = threadIdx.x;
  const int lane = tid & 63;
  const int w    = tid >> 6;
  const int lo   = lane & 31;
  const int hi   = lane >> 5;
  const int rsw  = lo & 7;

  unsigned char* W1L = LDS;
  unsigned char* HAw = LDS + 49152 + w * 12288;
  unsigned char* EAw = HAw + 8192;

  // ---- stage W1 into LDS once (48KB = 3072 chunks of 16B) ----
  #pragma unroll
  for (int j = 0; j < 6; ++j) {
    int ch = j * 512 + w * 64;
    async_copy16(Wp1 + (size_t)(ch + lane) * 8, LDS + ch * 16);
  }
  __syncthreads();                      // once per kernel; drains vmcnt

  const int gw     = blockIdx.x * 8 + w;
  const int nwaves = gridDim.x * 8;

  // contiguous balanced runs: wave gw gets T(+1) tiles starting at t0
  const int T  = ntiles / nwaves;
  const int r  = ntiles % nwaves;
  const int myT = T + (gw < r ? 1 : 0);
  const int t0  = gw * T + (gw < r ? gw : r);

  int    nodeA, nodeB;
  uint4  hregA[8], hregB[8];
  float4 aregA[8], aregB[8];

#define LOADIDX(t, NODE) \
  NODE = eidx[(size_t)(lane & 1) * E + (size_t)(t) * 32 + (lane >> 1)];

#define LOADEA(t, AREG) { \
  _Pragma("unroll") for (int it = 0; it < 8; ++it) \
    AREG[it] = *reinterpret_cast<const float4*>( \
        ea + (size_t)((t) * 32 + it * 4 + (lane >> 4)) * 64 + (lane & 15) * 4); }

#define GATHER(NODE, HREG) { \
  _Pragma("unroll") for (int it = 0; it < 8; ++it) { \
    int nd_ = __shfl(NODE, it * 8 + (lane >> 3), 64); \
    HREG[it] = *reinterpret_cast<const uint4*>( \
        hbf + (size_t)nd_ * 64 + (lane & 7) * 8); } }

#define STAGE(HREG, AREG) { \
  _Pragma("unroll") for (int it = 0; it < 8; ++it) { \
    int r_  = it * 4 + (lane >> 4); \
    int ch_ = lane & 15; \
    *reinterpret_cast<uint4*>(HAw + r_ * 256 + ((ch_ ^ (r_ & 7)) * 16)) = HREG[it]; \
  } \
  _Pragma("unroll") for (int it = 0; it < 8; ++it) { \
    int r_  = it * 4 + (lane >> 4); \
    int c8_ = lane & 15; \
    uint2 o_; \
    o_.x = cvt_pk_bf16(AREG[it].x, AREG[it].y); \
    o_.y = cvt_pk_bf16(AREG[it].z, AREG[it].w); \
    *reinterpret_cast<uint2*>( \
        EAw + r_ * 128 + (((c8_ >> 1) ^ (r_ & 7)) * 16) + (c8_ & 1) * 8) = o_; \
  } }

// BODY: stage+compute tile t; prefetch tile tn into NXT* banks if HN.
// GATHER for tn placed after GEMM1 so idx latency hides under 48 MFMAs.
#define BODY(t, tn, HN, CURH, CURA, NXTN, NXTH, NXTA) { \
  const int eb_ = (t) * 32; \
  if (HN) { LOADIDX(tn, NXTN) } \
  STAGE(CURH, CURA) \
  if (HN) { LOADEA(tn, NXTA) } \
  f32x16 acc[4]; \
  _Pragma("unroll") for (int m = 0; m < 4; ++m) acc[m] = (f32x16)0.0f; \
  _Pragma("unroll") for (int kk = 0; kk < 12; ++kk) { \
    bf16x8 bfr; \
    if (kk < 8) { \
      bfr = *reinterpret_cast<const bf16x8*>( \
          HAw + lo * 256 + (((kk * 2 + hi) ^ rsw) * 16)); \
    } else { \
      bfr = *reinterpret_cast<const bf16x8*>( \
          EAw + lo * 128 + ((((kk - 8) * 2 + hi) ^ rsw) * 16)); \
    } \
    _Pragma("unroll") for (int mt = 0; mt < 4; ++mt) { \
      bf16x8 afr = *reinterpret_cast<const bf16x8*>( \
          W1L + (size_t)(kk * 4 + mt) * 1024 + lane * 16); \
      acc[mt] = __builtin_amdgcn_mfma_f32_32x32x16_bf16(afr, bfr, acc[mt], 0, 0, 0); \
    } \
  } \
  if (HN) { GATHER(NXTN, NXTH) } \
  _Pragma("unroll") for (int c = 0; c < 16; ++c) { \
    int mt = c >> 2, g = c & 3; \
    int f0 = mt * 32 + g * 8 + hi * 4; \
    float4 bb = *reinterpret_cast<const float4*>(b1 + f0); \
    float s0 = shsp(acc[mt][g * 4 + 0] + bb.x); \
    float s1 = shsp(acc[mt][g * 4 + 1] + bb.y); \
    float s2 = shsp(acc[mt][g * 4 + 2] + bb.z); \
    float s3 = shsp(acc[mt][g * 4 + 3] + bb.w); \
    uint2 o_; \
    o_.x = cvt_pk_bf16(s0, s1); \
    o_.y = cvt_pk_bf16(s2, s3); \
    *reinterpret_cast<uint2*>(HAw + lo * 256 + ((c ^ rsw) * 16) + hi * 8) = o_; \
  } \
  f32x16 acc2[2]; \
  _Pragma("unroll") for (int m = 0; m < 2; ++m) acc2[m] = (f32x16)0.0f; \
  _Pragma("unroll") for (int kk = 0; kk < 8; ++kk) { \
    bf16x8 bfr = *reinterpret_cast<const bf16x8*>( \
        HAw + lo * 256 + (((kk * 2 + hi) ^ rsw) * 16)); \
    _Pragma("unroll") for (int mt = 0; mt < 2; ++mt) { \
      bf16x8 afr = *reinterpret_cast<const bf16x8*>( \
          Wp2 + ((size_t)(kk * 2 + mt) * 64 + lane) * 8); \
      acc2[mt] = __builtin_amdgcn_mfma_f32_32x32x16_bf16(afr, bfr, acc2[mt], 0, 0, 0); \
    } \
  } \
  _Pragma("unroll") for (int mt = 0; mt < 2; ++mt) { \
    _Pragma("unroll") for (int g = 0; g < 4; ++g) { \
      int oc0 = mt * 32 + g * 8 + hi * 4; \
      float4 bb = *reinterpret_cast<const float4*>(b2 + oc0); \
      float4 o_; \
      o_.x = acc2[mt][g * 4 + 0] + bb.x; \
      o_.y = acc2[mt][g * 4 + 1] + bb.y; \
      o_.z = acc2[mt][g * 4 + 2] + bb.z; \
      o_.w = acc2[mt][g * 4 + 3] + bb.w; \
      int c_ = mt * 8 + g * 2 + hi; \
      *reinterpret_cast<float4*>(HAw + lo * 256 + ((c_ ^ rsw) * 16)) = o_; \
    } \
  } \
  _Pragma("unroll") for (int it = 0; it < 8; ++it) { \
    int r_ = it * 4 + (lane >> 4); \
    int p_ = lane & 15; \
    float4 v_ = *reinterpret_cast<const float4*>(HAw + r_ * 256 + p_ * 16); \
    int c_ = p_ ^ (r_ & 7); \
    *reinterpret_cast<float4*>(out + (size_t)(eb_ + r_) * 64 + c_ * 4) = v_; \
  } }

  if (myT > 0) {
    LOADIDX(t0, nodeA)
    LOADEA(t0, aregA)
    GATHER(nodeA, hregA)
    for (int i = 0; i < myT; i += 2) {
      {
        const bool hn = (i + 1) < myT;
        BODY(t0 + i, t0 + i + 1, hn, hregA, aregA, nodeB, hregB, aregB)
      }
      if ((i + 1) < myT) {
        const bool hn = (i + 2) < myT;
        BODY(t0 + i + 1, t0 + i + 2, hn, hregB, aregB, nodeA, hregA, aregA)
      }
    }
  }
}

extern "C" void kernel_launch(void* const* d_in, const int* in_sizes, int n_in,
                              void* d_out, int out_size, void* d_ws, size_t ws_size,
                              hipStream_t stream) {
  const float* h  = (const float*)d_in[0];
  const float* ea = (const float*)d_in[1];
  const int*  idx = (const int*)d_in[2];
  const float* W1 = (const float*)d_in[3];
  const float* b1 = (const float*)d_in[4];
  const float* W2 = (const float*)d_in[5];
  const float* b2 = (const float*)d_in[6];
  float* out = (float*)d_out;

  const int N = in_sizes[0] / 64;      // 50000
  const int E = in_sizes[1] / 64;      // 800000

  unsigned short* hbf = (unsigned short*)d_ws;                       // N*64 bf16
  size_t off1 = (size_t)N * 64 * 2;
  unsigned short* Wp1 = (unsigned short*)((char*)d_ws + off1);       // 24576 bf16
  unsigned short* Wp2 = (unsigned short*)((char*)d_ws + off1 + 24576 * 2);

  int n4 = (N * 64) / 4;
  prep_h_kernel<<<(n4 + 255) / 256, 256, 0, stream>>>(h, hbf, n4);
  prep_w_kernel<<<16, 256, 0, stream>>>(W1, W2, Wp1, Wp2);

  int ntiles = E / 32;                  // 25000 wave-tiles
  edge_mlp_kernel<<<256, 512, 0, stream>>>(ea, idx, b1, b2, hbf, Wp1, Wp2,
                                           out, E, ntiles);
}

// Round 9
// 300.096 us; speedup vs baseline: 1.0104x; 1.0104x over previous
//
#include <hip/hip_runtime.h>
#include <cstddef>
#include <cstdint>

typedef __attribute__((ext_vector_type(8))) short bf16x8;   // 8 bf16 = 4 VGPR
typedef __attribute__((ext_vector_type(16))) float f32x16;  // MFMA 32x32 acc

static constexpr float LN2 = 0.69314718055994530942f;
static constexpr float INV_LN2 = 1.44269504088896340736f;

__device__ __forceinline__ unsigned short f2bf(float f) {
  unsigned int u = __float_as_uint(f);
  u += 0x7fffu + ((u >> 16) & 1u);   // RNE
  return (unsigned short)(u >> 16);
}

// v_cvt_pk_bf16_f32 (gfx950): D[15:0]=bf16(a), D[31:16]=bf16(b), RNE
__device__ __forceinline__ unsigned int cvt_pk_bf16(float a, float b) {
  unsigned int r;
  asm("v_cvt_pk_bf16_f32 %0, %1, %2" : "=v"(r) : "v"(a), "v"(b));
  return r;
}

__device__ __forceinline__ float hw_exp2(float x) {
  float r;
  asm("v_exp_f32 %0, %1" : "=v"(r) : "v"(x));
  return r;
}
__device__ __forceinline__ float hw_log2(float x) {
  float r;
  asm("v_log_f32 %0, %1" : "=v"(r) : "v"(x));
  return r;
}

// softplus(x)-ln2 = max(x,0)-ln2 + ln2*log2(1+2^(-|x|/ln2)); rel err ~1e-5
__device__ __forceinline__ float shsp(float x) {
  float t = hw_exp2(-fabsf(x) * INV_LN2);
  float l = hw_log2(1.0f + t);
  return fmaf(LN2, l, fmaxf(x, 0.0f) - LN2);
}

// async 16B global -> LDS (lane l writes lds + l*16)
__device__ __forceinline__ void async_copy16(const void* g, void* l) {
  __builtin_amdgcn_global_load_lds(
      (const __attribute__((address_space(1))) void*)g,
      (__attribute__((address_space(3))) void*)l, 16, 0, 0);
}

// ---- prep: h (N*64 f32) -> bf16 ----
__global__ void prep_h_kernel(const float* __restrict__ h,
                              unsigned short* __restrict__ hbf, int n4) {
  int i = blockIdx.x * 256 + threadIdx.x;
  if (i < n4) {
    float4 v = reinterpret_cast<const float4*>(h)[i];
    uint2 o;
    o.x = cvt_pk_bf16(v.x, v.y);
    o.y = cvt_pk_bf16(v.z, v.w);
    reinterpret_cast<uint2*>(hbf)[i] = o;
  }
}

// ---- prep: pack W1^T, W2^T into MFMA-fragment order (bf16), kk-major ----
__global__ void prep_w_kernel(const float* __restrict__ W1,
                              const float* __restrict__ W2,
                              unsigned short* __restrict__ Wp1,
                              unsigned short* __restrict__ Wp2) {
  int j = blockIdx.x * 256 + threadIdx.x;
  if (j < 48 * 64) {
    int f  = j / 64;
    int l  = j % 64;
    int kk = f >> 2;
    int mt = f & 3;
    int col = mt * 32 + (l & 31);
    int kb  = kk * 16 + (l >> 5) * 8;
    #pragma unroll
    for (int i = 0; i < 8; ++i)
      Wp1[(size_t)j * 8 + i] = f2bf(W1[(size_t)(kb + i) * 128 + col]);
  } else if (j < 48 * 64 + 16 * 64) {
    int jj = j - 48 * 64;
    int f  = jj / 64;
    int l  = jj % 64;
    int kk = f >> 1;
    int mt = f & 1;
    int oc = mt * 32 + (l & 31);
    int kb = kk * 16 + (l >> 5) * 8;
    #pragma unroll
    for (int i = 0; i < 8; ++i)
      Wp2[(size_t)jj * 8 + i] = f2bf(W2[(size_t)(kb + i) * 64 + oc]);
  }
}

// ---- main fused kernel: R7 structure + spill-free register prefetch ----
// 512 threads, 1 block/CU. LDS 144KB: [0,48K) W1 frags (staged once);
// per-wave 12KB (HAw 8K: h->X->out lifecycle; EAw 4K). STRIDED tile order
// (CU's 8 waves work 8 consecutive tiles -> L2-local ea/out streams).
// 1-tile-lookahead prefetch in static A/B VGPR banks; h-gather for t+1
// issued after GEMM1 so the idx round-trip hides under 48 MFMAs.
// __launch_bounds__(512,1): VGPR cap 512 -> no scratch spill (R8 lesson).
__global__ __launch_bounds__(512, 1)
void edge_mlp_kernel(const float* __restrict__ ea,
                     const int* __restrict__ eidx,
                     const float* __restrict__ b1,
                     const float* __restrict__ b2,
                     const unsigned short* __restrict__ hbf,
                     const unsigned short* __restrict__ Wp1,
                     const unsigned short* __restrict__ Wp2,
                     float* __restrict__ out,
                     int E, int ntiles) {
  __shared__ __align__(16) unsigned char LDS[147456];

  const int tid  = threadIdx.x;
  const int lane = tid & 63;
  const int w    = tid >> 6;
  const int lo   = lane & 31;
  const int hi   = lane >> 5;
  const int rsw  = lo & 7;

  unsigned char* W1L = LDS;
  unsigned char* HAw = LDS + 49152 + w * 12288;
  unsigned char* EAw = HAw + 8192;

  // ---- stage W1 into LDS once (48KB = 3072 chunks of 16B) ----
  #pragma unroll
  for (int j = 0; j < 6; ++j) {
    int ch = j * 512 + w * 64;
    async_copy16(Wp1 + (size_t)(ch + lane) * 8, LDS + ch * 16);
  }
  __syncthreads();                      // once per kernel; drains vmcnt

  const int gw     = blockIdx.x * 8 + w;
  const int nwaves = gridDim.x * 8;
  const int myT    = (gw < ntiles) ? (ntiles - gw + nwaves - 1) / nwaves : 0;

  int    nodeA, nodeB;
  uint4  hregA[8], hregB[8];
  float4 aregA[8], aregB[8];

#define LOADIDX(t, NODE) \
  NODE = eidx[(size_t)(lane & 1) * E + (size_t)(t) * 32 + (lane >> 1)];

#define LOADEA(t, AREG) { \
  _Pragma("unroll") for (int it = 0; it < 8; ++it) \
    AREG[it] = *reinterpret_cast<const float4*>( \
        ea + (size_t)((t) * 32 + it * 4 + (lane >> 4)) * 64 + (lane & 15) * 4); }

#define GATHER(NODE, HREG) { \
  _Pragma("unroll") for (int it = 0; it < 8; ++it) { \
    int nd_ = __shfl(NODE, it * 8 + (lane >> 3), 64); \
    HREG[it] = *reinterpret_cast<const uint4*>( \
        hbf + (size_t)nd_ * 64 + (lane & 7) * 8); } }

#define STAGE(HREG, AREG) { \
  _Pragma("unroll") for (int it = 0; it < 8; ++it) { \
    int r_  = it * 4 + (lane >> 4); \
    int ch_ = lane & 15; \
    *reinterpret_cast<uint4*>(HAw + r_ * 256 + ((ch_ ^ (r_ & 7)) * 16)) = HREG[it]; \
  } \
  _Pragma("unroll") for (int it = 0; it < 8; ++it) { \
    int r_  = it * 4 + (lane >> 4); \
    int c8_ = lane & 15; \
    uint2 o_; \
    o_.x = cvt_pk_bf16(AREG[it].x, AREG[it].y); \
    o_.y = cvt_pk_bf16(AREG[it].z, AREG[it].w); \
    *reinterpret_cast<uint2*>( \
        EAw + r_ * 128 + (((c8_ >> 1) ^ (r_ & 7)) * 16) + (c8_ & 1) * 8) = o_; \
  } }

// BODY: stage+compute tile t; prefetch tile tn into NXT* banks if HN.
#define BODY(t, tn, HN, CURH, CURA, NXTN, NXTH, NXTA) { \
  const int eb_ = (t) * 32; \
  if (HN) { LOADIDX(tn, NXTN) } \
  STAGE(CURH, CURA) \
  if (HN) { LOADEA(tn, NXTA) } \
  f32x16 acc[4]; \
  _Pragma("unroll") for (int m = 0; m < 4; ++m) acc[m] = (f32x16)0.0f; \
  _Pragma("unroll") for (int kk = 0; kk < 12; ++kk) { \
    bf16x8 bfr; \
    if (kk < 8) { \
      bfr = *reinterpret_cast<const bf16x8*>( \
          HAw + lo * 256 + (((kk * 2 + hi) ^ rsw) * 16)); \
    } else { \
      bfr = *reinterpret_cast<const bf16x8*>( \
          EAw + lo * 128 + ((((kk - 8) * 2 + hi) ^ rsw) * 16)); \
    } \
    _Pragma("unroll") for (int mt = 0; mt < 4; ++mt) { \
      bf16x8 afr = *reinterpret_cast<const bf16x8*>( \
          W1L + (size_t)(kk * 4 + mt) * 1024 + lane * 16); \
      acc[mt] = __builtin_amdgcn_mfma_f32_32x32x16_bf16(afr, bfr, acc[mt], 0, 0, 0); \
    } \
  } \
  if (HN) { GATHER(NXTN, NXTH) } \
  _Pragma("unroll") for (int c = 0; c < 16; ++c) { \
    int mt = c >> 2, g = c & 3; \
    int f0 = mt * 32 + g * 8 + hi * 4; \
    float4 bb = *reinterpret_cast<const float4*>(b1 + f0); \
    float s0 = shsp(acc[mt][g * 4 + 0] + bb.x); \
    float s1 = shsp(acc[mt][g * 4 + 1] + bb.y); \
    float s2 = shsp(acc[mt][g * 4 + 2] + bb.z); \
    float s3 = shsp(acc[mt][g * 4 + 3] + bb.w); \
    uint2 o_; \
    o_.x = cvt_pk_bf16(s0, s1); \
    o_.y = cvt_pk_bf16(s2, s3); \
    *reinterpret_cast<uint2*>(HAw + lo * 256 + ((c ^ rsw) * 16) + hi * 8) = o_; \
  } \
  f32x16 acc2[2]; \
  _Pragma("unroll") for (int m = 0; m < 2; ++m) acc2[m] = (f32x16)0.0f; \
  _Pragma("unroll") for (int kk = 0; kk < 8; ++kk) { \
    bf16x8 bfr = *reinterpret_cast<const bf16x8*>( \
        HAw + lo * 256 + (((kk * 2 + hi) ^ rsw) * 16)); \
    _Pragma("unroll") for (int mt = 0; mt < 2; ++mt) { \
      bf16x8 afr = *reinterpret_cast<const bf16x8*>( \
          Wp2 + ((size_t)(kk * 2 + mt) * 64 + lane) * 8); \
      acc2[mt] = __builtin_amdgcn_mfma_f32_32x32x16_bf16(afr, bfr, acc2[mt], 0, 0, 0); \
    } \
  } \
  _Pragma("unroll") for (int mt = 0; mt < 2; ++mt) { \
    _Pragma("unroll") for (int g = 0; g < 4; ++g) { \
      int oc0 = mt * 32 + g * 8 + hi * 4; \
      float4 bb = *reinterpret_cast<const float4*>(b2 + oc0); \
      float4 o_; \
      o_.x = acc2[mt][g * 4 + 0] + bb.x; \
      o_.y = acc2[mt][g * 4 + 1] + bb.y; \
      o_.z = acc2[mt][g * 4 + 2] + bb.z; \
      o_.w = acc2[mt][g * 4 + 3] + bb.w; \
      int c_ = mt * 8 + g * 2 + hi; \
      *reinterpret_cast<float4*>(HAw + lo * 256 + ((c_ ^ rsw) * 16)) = o_; \
    } \
  } \
  _Pragma("unroll") for (int it = 0; it < 8; ++it) { \
    int r_ = it * 4 + (lane >> 4); \
    int p_ = lane & 15; \
    float4 v_ = *reinterpret_cast<const float4*>(HAw + r_ * 256 + p_ * 16); \
    int c_ = p_ ^ (r_ & 7); \
    *reinterpret_cast<float4*>(out + (size_t)(eb_ + r_) * 64 + c_ * 4) = v_; \
  } }

  if (myT > 0) {
    const int t0 = gw;
    LOADIDX(t0, nodeA)
    LOADEA(t0, aregA)
    GATHER(nodeA, hregA)
    for (int i = 0; i < myT; i += 2) {
      {
        const int tc = gw + i * nwaves;
        const bool hn = (i + 1) < myT;
        BODY(tc, tc + nwaves, hn, hregA, aregA, nodeB, hregB, aregB)
      }
      if ((i + 1) < myT) {
        const int tc = gw + (i + 1) * nwaves;
        const bool hn = (i + 2) < myT;
        BODY(tc, tc + nwaves, hn, hregB, aregB, nodeA, hregA, aregA)
      }
    }
  }
}

extern "C" void kernel_launch(void* const* d_in, const int* in_sizes, int n_in,
                              void* d_out, int out_size, void* d_ws, size_t ws_size,
                              hipStream_t stream) {
  const float* h  = (const float*)d_in[0];
  const float* ea = (const float*)d_in[1];
  const int*  idx = (const int*)d_in[2];
  const float* W1 = (const float*)d_in[3];
  const float* b1 = (const float*)d_in[4];
  const float* W2 = (const float*)d_in[5];
  const float* b2 = (const float*)d_in[6];
  float* out = (float*)d_out;

  const int N = in_sizes[0] / 64;      // 50000
  const int E = in_sizes[1] / 64;      // 800000

  unsigned short* hbf = (unsigned short*)d_ws;                       // N*64 bf16
  size_t off1 = (size_t)N * 64 * 2;
  unsigned short* Wp1 = (unsigned short*)((char*)d_ws + off1);       // 24576 bf16
  unsigned short* Wp2 = (unsigned short*)((char*)d_ws + off1 + 24576 * 2);

  int n4 = (N * 64) / 4;
  prep_h_kernel<<<(n4 + 255) / 256, 256, 0, stream>>>(h, hbf, n4);
  prep_w_kernel<<<16, 256, 0, stream>>>(W1, W2, Wp1, Wp2);

  int ntiles = E / 32;                  // 25000 wave-tiles
  edge_mlp_kernel<<<256, 512, 0, stream>>>(ea, idx, b1, b2, hbf, Wp1, Wp2,
                                           out, E, ntiles);
}

// Round 10
// 180.984 us; speedup vs baseline: 1.6753x; 1.6581x over previous
//
#include <hip/hip_runtime.h>
#include <cstddef>
#include <cstdint>

typedef __attribute__((ext_vector_type(8))) short bf16x8;   // 8 bf16 = 4 VGPR
typedef __attribute__((ext_vector_type(16))) float f32x16;  // MFMA 32x32 acc

static constexpr float LN2 = 0.69314718055994530942f;
static constexpr float INV_LN2 = 1.44269504088896340736f;

__device__ __forceinline__ unsigned short f2bf(float f) {
  unsigned int u = __float_as_uint(f);
  u += 0x7fffu + ((u >> 16) & 1u);   // RNE
  return (unsigned short)(u >> 16);
}

// v_cvt_pk_bf16_f32 (gfx950): D[15:0]=bf16(a), D[31:16]=bf16(b), RNE
__device__ __forceinline__ unsigned int cvt_pk_bf16(float a, float b) {
  unsigned int r;
  asm("v_cvt_pk_bf16_f32 %0, %1, %2" : "=v"(r) : "v"(a), "v"(b));
  return r;
}

__device__ __forceinline__ float hw_exp2(float x) {
  float r;
  asm("v_exp_f32 %0, %1" : "=v"(r) : "v"(x));
  return r;
}
__device__ __forceinline__ float hw_log2(float x) {
  float r;
  asm("v_log_f32 %0, %1" : "=v"(r) : "v"(x));
  return r;
}

// softplus(x)-ln2 = max(x,0)-ln2 + ln2*log2(1+2^(-|x|/ln2)); rel err ~1e-5
__device__ __forceinline__ float shsp(float x) {
  float t = hw_exp2(-fabsf(x) * INV_LN2);
  float l = hw_log2(1.0f + t);
  return fmaf(LN2, l, fmaxf(x, 0.0f) - LN2);
}

// async 16B global -> LDS (lane l writes lds + l*16)
__device__ __forceinline__ void async_copy16(const void* g, void* l) {
  __builtin_amdgcn_global_load_lds(
      (const __attribute__((address_space(1))) void*)g,
      (__attribute__((address_space(3))) void*)l, 16, 0, 0);
}

// ---- prep: h (N*64 f32) -> bf16 ----
__global__ void prep_h_kernel(const float* __restrict__ h,
                              unsigned short* __restrict__ hbf, int n4) {
  int i = blockIdx.x * 256 + threadIdx.x;
  if (i < n4) {
    float4 v = reinterpret_cast<const float4*>(h)[i];
    uint2 o;
    o.x = cvt_pk_bf16(v.x, v.y);
    o.y = cvt_pk_bf16(v.z, v.w);
    reinterpret_cast<uint2*>(hbf)[i] = o;
  }
}

// ---- prep: pack W1^T, W2^T into MFMA-fragment order (bf16), kk-major ----
__global__ void prep_w_kernel(const float* __restrict__ W1,
                              const float* __restrict__ W2,
                              unsigned short* __restrict__ Wp1,
                              unsigned short* __restrict__ Wp2) {
  int j = blockIdx.x * 256 + threadIdx.x;
  if (j < 48 * 64) {
    int f  = j / 64;
    int l  = j % 64;
    int kk = f >> 2;
    int mt = f & 3;
    int col = mt * 32 + (l & 31);
    int kb  = kk * 16 + (l >> 5) * 8;
    #pragma unroll
    for (int i = 0; i < 8; ++i)
      Wp1[(size_t)j * 8 + i] = f2bf(W1[(size_t)(kb + i) * 128 + col]);
  } else if (j < 48 * 64 + 16 * 64) {
    int jj = j - 48 * 64;
    int f  = jj / 64;
    int l  = jj % 64;
    int kk = f >> 1;
    int mt = f & 1;
    int oc = mt * 32 + (l & 31);
    int kb = kk * 16 + (l >> 5) * 8;
    #pragma unroll
    for (int i = 0; i < 8; ++i)
      Wp2[(size_t)jj * 8 + i] = f2bf(W2[(size_t)(kb + i) * 64 + oc]);
  }
}

// ---- main fused kernel: R7 structure at 12 waves/CU (3 per SIMD) ----
// 768 threads, 1 block/CU. LDS 144KB = [0,48K) W1 frags (staged once) +
// 12 waves x 8KB HAw (h -> X -> out lifecycle, wave-private, XOR-swizzled).
// edge_attr kept in VGPRs per-lane (no EAw): frag kk>=8 built by cvt_pk at
// use (R6-verified mapping). Strided tile order; no barriers in the loop;
// no VGPR prefetch banks (R8/R9: compiler pins 128 VGPRs and spills them).
__global__ __launch_bounds__(768, 1)
void edge_mlp_kernel(const float* __restrict__ ea,
                     const int* __restrict__ eidx,
                     const float* __restrict__ b1,
                     const float* __restrict__ b2,
                     const unsigned short* __restrict__ hbf,
                     const unsigned short* __restrict__ Wp1,
                     const unsigned short* __restrict__ Wp2,
                     float* __restrict__ out,
                     int E, int ntiles) {
  __shared__ __align__(16) unsigned char LDS[147456];

  const int tid  = threadIdx.x;
  const int lane = tid & 63;
  const int w    = tid >> 6;          // 0..11
  const int lo   = lane & 31;
  const int hi   = lane >> 5;
  const int rsw  = lo & 7;

  unsigned char* W1L = LDS;
  unsigned char* HAw = LDS + 49152 + w * 8192;

  // ---- stage W1 into LDS once (48KB = 3072 chunks of 16B, 12 waves) ----
  #pragma unroll
  for (int j = 0; j < 4; ++j) {
    int ch = j * 768 + w * 64;
    async_copy16(Wp1 + (size_t)(ch + lane) * 8, LDS + ch * 16);
  }
  __syncthreads();                      // once per kernel; drains vmcnt

  const int gw     = blockIdx.x * 12 + w;
  const int nwaves = gridDim.x * 12;

  for (int t = gw; t < ntiles; t += nwaves) {
    const int eb = t * 32;

    // ---- edge_attr per-lane: lane (lo,hi) holds ea[eb+lo][hi*8 + j16*16 ..] ----
    float4 areg[8];
    const float* eab = ea + (size_t)(eb + lo) * 64;
    #pragma unroll
    for (int j = 0; j < 4; ++j) {
      areg[2 * j]     = *reinterpret_cast<const float4*>(eab + j * 16 + hi * 8);
      areg[2 * j + 1] = *reinterpret_cast<const float4*>(eab + j * 16 + hi * 8 + 4);
    }

    // ---- node ids: lane l -> (row=l>>1, side=l&1), 2x128B segments ----
    int node = eidx[(size_t)(lane & 1) * E + eb + (lane >> 1)];

    // ---- h gather, coalesced: 8 segments of 128B per instr ----
    uint4 hreg[8];
    #pragma unroll
    for (int it = 0; it < 8; ++it) {
      int nd = __shfl(node, it * 8 + (lane >> 3), 64);
      hreg[it] = *reinterpret_cast<const uint4*>(
          hbf + (size_t)nd * 64 + (lane & 7) * 8);
    }

    // ---- ds_write h: row r = it*4+(lane>>4), chunk ch = lane&15 ----
    #pragma unroll
    for (int it = 0; it < 8; ++it) {
      int r  = it * 4 + (lane >> 4);
      int ch = lane & 15;
      *reinterpret_cast<uint4*>(HAw + r * 256 + ((ch ^ (r & 7)) * 16)) = hreg[it];
    }
    // wave-local ds_write -> ds_read ordering via lgkmcnt; no barrier

    // ---- GEMM1: x^T = W1^T(128x192) @ concat^T ----
    f32x16 acc[4];
    #pragma unroll
    for (int m = 0; m < 4; ++m) acc[m] = (f32x16)0.0f;

    #pragma unroll
    for (int kk = 0; kk < 12; ++kk) {
      bf16x8 bfr;
      if (kk < 8) {
        bfr = *reinterpret_cast<const bf16x8*>(
            HAw + lo * 256 + (((kk * 2 + hi) ^ rsw) * 16));
      } else {
        float4 lo4 = areg[(kk - 8) * 2];
        float4 hi4 = areg[(kk - 8) * 2 + 1];
        union { bf16x8 v; unsigned u[4]; } tt;
        tt.u[0] = cvt_pk_bf16(lo4.x, lo4.y);
        tt.u[1] = cvt_pk_bf16(lo4.z, lo4.w);
        tt.u[2] = cvt_pk_bf16(hi4.x, hi4.y);
        tt.u[3] = cvt_pk_bf16(hi4.z, hi4.w);
        bfr = tt.v;
      }
      #pragma unroll
      for (int mt = 0; mt < 4; ++mt) {
        bf16x8 afr = *reinterpret_cast<const bf16x8*>(
            W1L + (size_t)(kk * 4 + mt) * 1024 + lane * 16);
        acc[mt] = __builtin_amdgcn_mfma_f32_32x32x16_bf16(afr, bfr, acc[mt], 0, 0, 0);
      }
    }

    // ---- epilogue 1: bias + softplus -> bf16 X rows (alias HAw) ----
    #pragma unroll
    for (int c = 0; c < 16; ++c) {
      int mt = c >> 2, g = c & 3;
      int f0 = mt * 32 + g * 8 + hi * 4;
      float4 bb = *reinterpret_cast<const float4*>(b1 + f0);
      float s0 = shsp(acc[mt][g * 4 + 0] + bb.x);
      float s1 = shsp(acc[mt][g * 4 + 1] + bb.y);
      float s2 = shsp(acc[mt][g * 4 + 2] + bb.z);
      float s3 = shsp(acc[mt][g * 4 + 3] + bb.w);
      uint2 o;
      o.x = cvt_pk_bf16(s0, s1);
      o.y = cvt_pk_bf16(s2, s3);
      *reinterpret_cast<uint2*>(HAw + lo * 256 + ((c ^ rsw) * 16) + hi * 8) = o;
    }

    // ---- GEMM2: out^T = W2^T(64x128) @ x (W2 frags from global/L1) ----
    f32x16 acc2[2];
    #pragma unroll
    for (int m = 0; m < 2; ++m) acc2[m] = (f32x16)0.0f;

    #pragma unroll
    for (int kk = 0; kk < 8; ++kk) {
      bf16x8 bfr = *reinterpret_cast<const bf16x8*>(
          HAw + lo * 256 + (((kk * 2 + hi) ^ rsw) * 16));
      #pragma unroll
      for (int mt = 0; mt < 2; ++mt) {
        bf16x8 afr = *reinterpret_cast<const bf16x8*>(
            Wp2 + ((size_t)(kk * 2 + mt) * 64 + lane) * 8);
        acc2[mt] = __builtin_amdgcn_mfma_f32_32x32x16_bf16(afr, bfr, acc2[mt], 0, 0, 0);
      }
    }

    // ---- epilogue 2: bias -> f32 out rows in LDS (alias HAw again) ----
    #pragma unroll
    for (int mt = 0; mt < 2; ++mt) {
      #pragma unroll
      for (int g = 0; g < 4; ++g) {
        int oc0 = mt * 32 + g * 8 + hi * 4;
        float4 bb = *reinterpret_cast<const float4*>(b2 + oc0);
        float4 o;
        o.x = acc2[mt][g * 4 + 0] + bb.x;
        o.y = acc2[mt][g * 4 + 1] + bb.y;
        o.z = acc2[mt][g * 4 + 2] + bb.z;
        o.w = acc2[mt][g * 4 + 3] + bb.w;
        int c = mt * 8 + g * 2 + hi;          // 16B f32 chunk index
        *reinterpret_cast<float4*>(HAw + lo * 256 + ((c ^ rsw) * 16)) = o;
      }
    }

    // ---- coalesced store: 1KB contiguous per instr (permuted in-row) ----
    #pragma unroll
    for (int it = 0; it < 8; ++it) {
      int r = it * 4 + (lane >> 4);
      int p = lane & 15;
      float4 v = *reinterpret_cast<const float4*>(HAw + r * 256 + p * 16);
      int c = p ^ (r & 7);
      *reinterpret_cast<float4*>(out + (size_t)(eb + r) * 64 + c * 4) = v;
    }
  }
}

extern "C" void kernel_launch(void* const* d_in, const int* in_sizes, int n_in,
                              void* d_out, int out_size, void* d_ws, size_t ws_size,
                              hipStream_t stream) {
  const float* h  = (const float*)d_in[0];
  const float* ea = (const float*)d_in[1];
  const int*  idx = (const int*)d_in[2];
  const float* W1 = (const float*)d_in[3];
  const float* b1 = (const float*)d_in[4];
  const float* W2 = (const float*)d_in[5];
  const float* b2 = (const float*)d_in[6];
  float* out = (float*)d_out;

  const int N = in_sizes[0] / 64;      // 50000
  const int E = in_sizes[1] / 64;      // 800000

  unsigned short* hbf = (unsigned short*)d_ws;                       // N*64 bf16
  size_t off1 = (size_t)N * 64 * 2;
  unsigned short* Wp1 = (unsigned short*)((char*)d_ws + off1);       // 24576 bf16
  unsigned short* Wp2 = (unsigned short*)((char*)d_ws + off1 + 24576 * 2);

  int n4 = (N * 64) / 4;
  prep_h_kernel<<<(n4 + 255) / 256, 256, 0, stream>>>(h, hbf, n4);
  prep_w_kernel<<<16, 256, 0, stream>>>(W1, W2, Wp1, Wp2);

  int ntiles = E / 32;                  // 25000 wave-tiles
  edge_mlp_kernel<<<256, 768, 0, stream>>>(ea, idx, b1, b2, hbf, Wp1, Wp2,
                                           out, E, ntiles);
}